// Round 10
// baseline (273.660 us; speedup 1.0000x reference)
//
#include <hip/hip_runtime.h>

#define IN_DIM 784
#define NDB 25                 // dim-blocks of 32 (784 = 24*32 + 16 exactly)
#define NUNITS (NDB*9)         // 225 (db,c) units of 32 k
#define BATCH 16384
#define NOUTC 160              // HEADS*OUT_DIM
#define HEADS 10
#define KSPLIT 5
#define DBPY 5                 // db per y-slice (5*5 = 25)
#define UNITB 10240            // bytes of B per (db,c) unit: 32k x 160n x 2B

typedef __attribute__((ext_vector_type(8))) short bf16x8;
typedef __attribute__((ext_vector_type(4))) float f32x4;
typedef __attribute__((ext_vector_type(16))) float f32x16;
typedef __attribute__((ext_vector_type(4))) unsigned int u32x4;

__device__ __forceinline__ unsigned short f2bf(float f) {
    unsigned u = __builtin_bit_cast(unsigned, f);
    unsigned r = 0x7FFFu + ((u >> 16) & 1u);
    return (unsigned short)((u + r) >> 16);
}

__device__ __forceinline__ void gload_lds16(const void* g, void* s) {
    __builtin_amdgcn_global_load_lds(
        (const __attribute__((address_space(1))) unsigned int*)g,
        (__attribute__((address_space(3))) unsigned int*)s, 16, 0, 0);
}

// ---------------- weight packing: W -> 32x32x16 MFMA B-fragment layout -------
// unit kc = db*9 + c; fragment f = (kc*2 + kh)*5 + nt.
// B-frag: lane l elem j: d = db*32 + kh*16 + (l>>5)*8 + j ; n = nt*32 + (l&31)
// 1/6 spline constant folded here. [layout verified r5/r9 pass]
__global__ void k_wprep(const float* __restrict__ coef, const float* __restrict__ scale_base,
                        const float* __restrict__ scale_sp, const float* __restrict__ mask,
                        unsigned short* __restrict__ Wp) {
    int tid = blockIdx.x * blockDim.x + threadIdx.x;
    if (tid >= NUNITS * 32 * NOUTC) return;     // 1,152,000
    int frag = tid >> 9;
    int rem  = tid & 511;
    int l = rem >> 3, j = rem & 7;
    int nt = frag % 5;
    int t2 = frag / 5;
    int kh = t2 & 1;
    int kc = t2 >> 1;
    int db = kc / 9, c = kc - db * 9;
    int d = db * 32 + kh * 16 + ((l >> 5) << 3) + j;
    int n = nt * 32 + (l & 31);
    float v = 0.f;
    if (d < IN_DIM) {
        int h = n >> 4, o = n & 15;
        size_t base = ((size_t)h * IN_DIM + d) * 16 + o;
        float m = mask[base];
        v = (c == 0) ? scale_base[base] * m
                     : coef[base * 8 + (c - 1)] * scale_sp[base] * m * 0.16666667f;
    }
    Wp[tid] = f2bf(v);
}

// ---------------- fused: A-frags in registers, B via LDS unit double-buffer --
// 128 thr = 2 waves; wave w owns rows [bx*64 + w*32, +32) x all 160 cols.
// acc = 5 x f32x16 = 80 (AGPR). Grid 1280 blocks = 5 blocks/CU, 10 waves/CU:
// the per-unit barrier drain (vmcnt(0)) of one block overlaps 4 other blocks'
// compute -- this cross-block overlap is the r9 fix (r9: 2 blocks/CU, convoy).
__global__ void __launch_bounds__(128, 4) k_fused(const float* __restrict__ x,
                                                  const float* __restrict__ gridp,
                                                  const unsigned short* __restrict__ Wp,
                                                  float* __restrict__ part) {
    __shared__ __attribute__((aligned(16))) char ldsB[2][UNITB];
    const int tid = threadIdx.x;
    const int l = tid & 63, wid = tid >> 6;
    const int la = l & 31, lb = l >> 5;
    const int row0 = blockIdx.x * 64 + wid * 32 + la;   // this lane's row
    const int y = blockIdx.y;
    const int db0 = y * DBPY, db1 = db0 + DBPY;

    const float g0 = gridp[0];
    const float ih = 1.f / (gridp[1] - g0);
    const float nihg0 = -g0 * ih;

    f32x16 acc[5];
    #pragma unroll
    for (int nt = 0; nt < 5; ++nt)
        #pragma unroll
        for (int j = 0; j < 16; ++j) acc[nt][j] = 0.f;

    const float* xrow = x + (size_t)row0 * IN_DIM;
    const char* wpb = (const char*)Wp;

    // eval state per kh: 8 dims -> packed spline pair (w0,w1|w2,w3), packed m+8
    unsigned long long wp[2][8];
    unsigned mp[2][2];          // m+8 bytes, 4 per dword
    unsigned sf[2][4];          // packed silu (live only within c==0 phase)
    f32x4 xq[2][2];

    auto xload = [&](int db) {
        #pragma unroll
        for (int kh = 0; kh < 2; ++kh) {
            if (db * 32 + kh * 16 < IN_DIM) {
                const int d0 = db * 32 + kh * 16 + lb * 8;
                xq[kh][0] = *(const f32x4*)(xrow + d0);
                xq[kh][1] = *(const f32x4*)(xrow + d0 + 4);
            }
        }
    };

    auto evalkh = [&](int kh) {
        float sil8[8];
        unsigned m0 = 0u, m1 = 0u;
        #pragma unroll
        for (int jj = 0; jj < 8; ++jj) {
            const float xv = (jj < 4) ? xq[kh][0][jj] : xq[kh][1][jj - 4];
            const float u = fmaf(xv, ih, nihg0);
            const float fm = floorf(u);
            int m = (int)fm;
            m = m < -8 ? -8 : (m > 24 ? 24 : m);
            const float t = u - fm;
            const float w0 = t * t * t;
            const float w1 = fmaf(fmaf(fmaf(-3.f, t, 3.f), t, 3.f), t, 1.f);
            const float w2 = fmaf(fmaf(3.f, t, -6.f) * t, t, 4.f);
            const float omt = 1.f - t;
            const float w3 = omt * omt * omt;
            const float den = 1.f + __expf(-xv);
            float inv; asm("v_rcp_f32 %0, %1" : "=v"(inv) : "v"(den));
            sil8[jj] = xv * inv;
            unsigned p01, p23;
            asm("v_cvt_pk_bf16_f32 %0, %1, %2" : "=v"(p01) : "v"(w0), "v"(w1));
            asm("v_cvt_pk_bf16_f32 %0, %1, %2" : "=v"(p23) : "v"(w2), "v"(w3));
            wp[kh][jj] = (unsigned long long)p01 | ((unsigned long long)p23 << 32);
            const unsigned mb = (unsigned)(m + 8);
            if (jj < 4) m0 |= mb << (jj * 8); else m1 |= mb << ((jj - 4) * 8);
        }
        mp[kh][0] = m0; mp[kh][1] = m1;
        #pragma unroll
        for (int pr = 0; pr < 4; ++pr) {
            unsigned ps;
            asm("v_cvt_pk_bf16_f32 %0, %1, %2" : "=v"(ps) : "v"(sil8[2*pr]), "v"(sil8[2*pr+1]));
            sf[kh][pr] = ps;
        }
    };

    // A-frag build: elem j of plane c = wsel[m_j-(c-1)] (0 if out of [0,3])
    auto buildA = [&](int kh, int c) -> bf16x8 {
        u32x4 fw;
        if (c == 0) {
            fw = (u32x4){sf[kh][0], sf[kh][1], sf[kh][2], sf[kh][3]};
        } else {
            const unsigned sub = (unsigned)(7 + c);   // idx = (m+8) - (7+c)
            #pragma unroll
            for (int pr = 0; pr < 4; ++pr) {
                unsigned lo, hi;
                {
                    const int j = 2 * pr;
                    const unsigned stored = (mp[kh][j >> 2] >> ((j & 3) * 8)) & 0xFFu;
                    const unsigned idx = stored - sub;            // wraps if negative
                    const unsigned amt = (idx << 4) & 63u;
                    lo = (unsigned)(wp[kh][j] >> amt) & 0xFFFFu;
                    lo = (idx <= 3u) ? lo : 0u;
                }
                {
                    const int j = 2 * pr + 1;
                    const unsigned stored = (mp[kh][j >> 2] >> ((j & 3) * 8)) & 0xFFu;
                    const unsigned idx = stored - sub;
                    const unsigned amt = (idx << 4) & 63u;
                    hi = (unsigned)(wp[kh][j] >> amt) & 0xFFFFu;
                    hi = (idx <= 3u) ? hi : 0u;
                }
                fw[pr] = lo | (hi << 16);
            }
        }
        return __builtin_bit_cast(bf16x8, fw);
    };

    // stage one (db,c) unit (10 KB) into buf pb: 10 x 1KB chunks over 2 waves
    auto stage = [&](int pb, int db, int c) {
        const char* src = wpb + (size_t)(db * 9 + c) * UNITB + (size_t)l * 16;
        char* dst = &ldsB[pb][0];
        #pragma unroll
        for (int ch = 0; ch < 5; ++ch)
            gload_lds16(src + (size_t)(wid + 2 * ch) * 1024, dst + (wid + 2 * ch) * 1024);
    };

    // prologue
    xload(db0);
    stage(0, db0, 0);
    __syncthreads();

    int p = 0;
    #pragma unroll 1
    for (int u = 0; u < DBPY * 9; ++u) {
        const int db = db0 + u / 9;
        const int c  = u - 9 * (u / 9);
        if (u + 1 < DBPY * 9)
            stage(p ^ 1, db0 + (u + 1) / 9, (u + 1) % 9);
        if (c == 0) {
            evalkh(0);
            evalkh(1);                        // db==24: stale xq[1], unused below
            if (db + 1 < db1) xload(db + 1);  // prefetch next db's x (xq now free)
        }
        #pragma unroll
        for (int kh = 0; kh < 2; ++kh) {
            if (kh == 0 || db < 24) {
                const bf16x8 a = buildA(kh, c);
                const char* bp = &ldsB[p][kh * 5120] + l * 16;
                #pragma unroll
                for (int nt = 0; nt < 5; ++nt) {
                    const bf16x8 b = *(const bf16x8*)(bp + nt * 1024);
                    acc[nt] = __builtin_amdgcn_mfma_f32_32x32x16_bf16(a, b, acc[nt], 0, 0, 0);
                }
            }
        }
        __syncthreads();
        p ^= 1;
    }

    // ---- store: C/D 32x32: col = nt*32 + la, row = (r&3) + 8*(r>>2) + 4*lb --
    float* pp = part + (size_t)y * BATCH * NOUTC;
    const int rowb = blockIdx.x * 64 + wid * 32;
    #pragma unroll
    for (int nt = 0; nt < 5; ++nt) {
        #pragma unroll
        for (int r = 0; r < 16; ++r) {
            const int rl = (r & 3) + 8 * (r >> 2) + 4 * lb;
            pp[(size_t)(rowb + rl) * NOUTC + nt * 32 + la] = acc[nt][r];
        }
    }
}

// ---------------- epilogue MLP: sum partials, tanh -> 16x8 -> tanh -> 8x1 ----
__global__ void k_epi(const float* __restrict__ part, const float* __restrict__ w1,
                      const float* __restrict__ b1, const float* __restrict__ w2,
                      const float* __restrict__ b2, float* __restrict__ out) {
    int t = blockIdx.x * blockDim.x + threadIdx.x;
    if (t >= BATCH * HEADS) return;
    int b = t / HEADS;
    int h = t - b * HEADS;
    const f32x4* P = (const f32x4*)part;
    const int vbase = b * (NOUTC / 4) + h * 4;
    float y[16];
    #pragma unroll
    for (int c4 = 0; c4 < 4; ++c4) {
        f32x4 v = P[vbase + c4];
        #pragma unroll
        for (int s = 1; s < KSPLIT; ++s) {
            f32x4 v2 = P[(size_t)s * BATCH * (NOUTC / 4) + vbase + c4];
            v.x += v2.x; v.y += v2.y; v.z += v2.z; v.w += v2.w;
        }
        y[c4 * 4 + 0] = tanhf(v.x); y[c4 * 4 + 1] = tanhf(v.y);
        y[c4 * 4 + 2] = tanhf(v.z); y[c4 * 4 + 3] = tanhf(v.w);
    }
    float oacc = b2[h];
    #pragma unroll
    for (int p = 0; p < 8; ++p) {
        float a = b1[h * 8 + p];
        const float* wr = w1 + ((size_t)h * 8 + p) * 16;
        #pragma unroll
        for (int o = 0; o < 16; ++o) a = fmaf(y[o], wr[o], a);
        oacc = fmaf(tanhf(a), w2[h * 8 + p], oacc);
    }
    out[t] = oacc;
}

extern "C" void kernel_launch(void* const* d_in, const int* in_sizes, int n_in,
                              void* d_out, int out_size, void* d_ws, size_t ws_size,
                              hipStream_t stream) {
    const float* x          = (const float*)d_in[0];
    const float* gridp      = (const float*)d_in[1];
    const float* coef       = (const float*)d_in[2];
    const float* scale_base = (const float*)d_in[3];
    const float* scale_sp   = (const float*)d_in[4];
    const float* mask       = (const float*)d_in[5];
    const float* w1         = (const float*)d_in[6];
    const float* b1         = (const float*)d_in[7];
    const float* w2         = (const float*)d_in[8];
    const float* b2         = (const float*)d_in[9];
    float* out = (float*)d_out;

    char* ws = (char*)d_ws;
    float* part        = (float*)ws;                          // 5*16384*160*4 = 52,428,800 B
    unsigned short* Wp = (unsigned short*)(ws + 52428800);    // 225*32*160*2  =  2,304,000 B

    k_wprep<<<dim3((NUNITS * 32 * NOUTC + 255) / 256), dim3(256), 0, stream>>>(coef, scale_base, scale_sp, mask, Wp);
    k_fused<<<dim3(BATCH / 64, KSPLIT), dim3(128), 0, stream>>>(x, gridp, Wp, part);
    k_epi  <<<dim3((BATCH * HEADS + 255) / 256), dim3(256), 0, stream>>>(part, w1, b1, w2, b2, out);
}

// Round 11
// 136.187 us; speedup vs baseline: 2.0094x; 2.0094x over previous
//
#include <hip/hip_runtime.h>

#define IN_DIM 784
#define NDB 25                 // dim-blocks of 32 (784 = 24*32 + 16 exactly)
#define NUNITS (NDB*9)         // 225 (db,c) units of 32 k
#define BATCH 16384
#define NOUTC 160              // HEADS*OUT_DIM
#define HEADS 10
#define KSPLIT 5
#define DBPY 5                 // db per y-slice (5*5 = 25)
#define NU (DBPY*9)            // 45 units per slice
#define UNITB 10240            // bytes of B per (db,c) unit: 32k x 160n x 2B

typedef __attribute__((ext_vector_type(8))) short bf16x8;
typedef __attribute__((ext_vector_type(4))) float f32x4;
typedef __attribute__((ext_vector_type(16))) float f32x16;
typedef __attribute__((ext_vector_type(4))) unsigned int u32x4;

__device__ __forceinline__ unsigned short f2bf(float f) {
    unsigned u = __builtin_bit_cast(unsigned, f);
    unsigned r = 0x7FFFu + ((u >> 16) & 1u);
    return (unsigned short)((u + r) >> 16);
}

__device__ __forceinline__ void gload_lds16(const void* g, void* s) {
    __builtin_amdgcn_global_load_lds(
        (const __attribute__((address_space(1))) unsigned int*)g,
        (__attribute__((address_space(3))) unsigned int*)s, 16, 0, 0);
}

// ---------------- weight packing: W -> 32x32x16 MFMA B-fragment layout -------
// unit kc = db*9 + c; fragment f = (kc*2 + kh)*5 + nt.
// B-frag: lane l elem j: d = db*32 + kh*16 + (l>>5)*8 + j ; n = nt*32 + (l&31)
// 1/6 spline constant folded here. [layout verified r5/r9/r10 pass]
__global__ void k_wprep(const float* __restrict__ coef, const float* __restrict__ scale_base,
                        const float* __restrict__ scale_sp, const float* __restrict__ mask,
                        unsigned short* __restrict__ Wp) {
    int tid = blockIdx.x * blockDim.x + threadIdx.x;
    if (tid >= NUNITS * 32 * NOUTC) return;     // 1,152,000
    int frag = tid >> 9;
    int rem  = tid & 511;
    int l = rem >> 3, j = rem & 7;
    int nt = frag % 5;
    int t2 = frag / 5;
    int kh = t2 & 1;
    int kc = t2 >> 1;
    int db = kc / 9, c = kc - db * 9;
    int d = db * 32 + kh * 16 + ((l >> 5) << 3) + j;
    int n = nt * 32 + (l & 31);
    float v = 0.f;
    if (d < IN_DIM) {
        int h = n >> 4, o = n & 15;
        size_t base = ((size_t)h * IN_DIM + d) * 16 + o;
        float m = mask[base];
        v = (c == 0) ? scale_base[base] * m
                     : coef[base * 8 + (c - 1)] * scale_sp[base] * m * 0.16666667f;
    }
    Wp[tid] = f2bf(v);
}

// ---------------- fused: A-frags in registers, B via LDS unit double-buffer --
// 128 thr = 2 waves; wave w owns rows [bx*64 + w*32, +32) x all 160 cols.
// T3/T4 schedule (m201 pattern): raw s_barrier (NO vmcnt drain) + counted
// s_waitcnt vmcnt(5): stage(u+1) stays in flight across both barriers.
// Barrier A: both waves' stage(u) retired before reads of buf[u&1].
// Barrier B: reads of buf[u&1] done before next iteration's stage overwrites.
// launch_bounds(128,2): 256-reg cap -> no acc spill (r10 lesson, rule #15).
__global__ void __launch_bounds__(128, 2) k_fused(const float* __restrict__ x,
                                                  const float* __restrict__ gridp,
                                                  const unsigned short* __restrict__ Wp,
                                                  float* __restrict__ part) {
    __shared__ __attribute__((aligned(16))) char ldsB[2][UNITB];
    const int tid = threadIdx.x;
    const int l = tid & 63, wid = tid >> 6;
    const int la = l & 31, lb = l >> 5;
    const int row0 = blockIdx.x * 64 + wid * 32 + la;   // this lane's row
    const int y = blockIdx.y;
    const int db0 = y * DBPY, db1 = db0 + DBPY;

    const float g0 = gridp[0];
    const float ih = 1.f / (gridp[1] - g0);
    const float nihg0 = -g0 * ih;

    f32x16 acc[5];
    #pragma unroll
    for (int nt = 0; nt < 5; ++nt)
        #pragma unroll
        for (int j = 0; j < 16; ++j) acc[nt][j] = 0.f;

    const float* xrow = x + (size_t)row0 * IN_DIM;
    const char* wpb = (const char*)Wp;

    // eval state per kh: 8 dims -> packed spline pair (w0,w1|w2,w3), packed m+8
    unsigned long long wp[2][8];
    unsigned mp[2][2];          // m+8 bytes, 4 per dword
    unsigned sf[2][4];          // packed silu (live only within c==0 phase)
    f32x4 xq[2][2];

    auto xload = [&](int db) {
        #pragma unroll
        for (int kh = 0; kh < 2; ++kh) {
            if (db * 32 + kh * 16 < IN_DIM) {
                const int d0 = db * 32 + kh * 16 + lb * 8;
                xq[kh][0] = *(const f32x4*)(xrow + d0);
                xq[kh][1] = *(const f32x4*)(xrow + d0 + 4);
            }
        }
    };

    auto evalkh = [&](int kh) {
        float sil8[8];
        unsigned m0 = 0u, m1 = 0u;
        #pragma unroll
        for (int jj = 0; jj < 8; ++jj) {
            const float xv = (jj < 4) ? xq[kh][0][jj] : xq[kh][1][jj - 4];
            const float u = fmaf(xv, ih, nihg0);
            const float fm = floorf(u);
            int m = (int)fm;
            m = m < -8 ? -8 : (m > 24 ? 24 : m);
            const float t = u - fm;
            const float w0 = t * t * t;
            const float w1 = fmaf(fmaf(fmaf(-3.f, t, 3.f), t, 3.f), t, 1.f);
            const float w2 = fmaf(fmaf(3.f, t, -6.f) * t, t, 4.f);
            const float omt = 1.f - t;
            const float w3 = omt * omt * omt;
            const float den = 1.f + __expf(-xv);
            float inv; asm("v_rcp_f32 %0, %1" : "=v"(inv) : "v"(den));
            sil8[jj] = xv * inv;
            unsigned p01, p23;
            asm("v_cvt_pk_bf16_f32 %0, %1, %2" : "=v"(p01) : "v"(w0), "v"(w1));
            asm("v_cvt_pk_bf16_f32 %0, %1, %2" : "=v"(p23) : "v"(w2), "v"(w3));
            wp[kh][jj] = (unsigned long long)p01 | ((unsigned long long)p23 << 32);
            const unsigned mb = (unsigned)(m + 8);
            if (jj < 4) m0 |= mb << (jj * 8); else m1 |= mb << ((jj - 4) * 8);
        }
        mp[kh][0] = m0; mp[kh][1] = m1;
        #pragma unroll
        for (int pr = 0; pr < 4; ++pr) {
            unsigned ps;
            asm("v_cvt_pk_bf16_f32 %0, %1, %2" : "=v"(ps) : "v"(sil8[2*pr]), "v"(sil8[2*pr+1]));
            sf[kh][pr] = ps;
        }
    };

    // A-frag build: elem j of plane c = wsel[m_j-(c-1)] (0 if out of [0,3])
    auto buildA = [&](int kh, int c) -> bf16x8 {
        u32x4 fw;
        if (c == 0) {
            fw = (u32x4){sf[kh][0], sf[kh][1], sf[kh][2], sf[kh][3]};
        } else {
            const unsigned sub = (unsigned)(7 + c);   // idx = (m+8) - (7+c)
            #pragma unroll
            for (int pr = 0; pr < 4; ++pr) {
                unsigned lo, hi;
                {
                    const int j = 2 * pr;
                    const unsigned stored = (mp[kh][j >> 2] >> ((j & 3) * 8)) & 0xFFu;
                    const unsigned idx = stored - sub;            // wraps if negative
                    const unsigned amt = (idx << 4) & 63u;
                    lo = (unsigned)(wp[kh][j] >> amt) & 0xFFFFu;
                    lo = (idx <= 3u) ? lo : 0u;
                }
                {
                    const int j = 2 * pr + 1;
                    const unsigned stored = (mp[kh][j >> 2] >> ((j & 3) * 8)) & 0xFFu;
                    const unsigned idx = stored - sub;
                    const unsigned amt = (idx << 4) & 63u;
                    hi = (unsigned)(wp[kh][j] >> amt) & 0xFFFFu;
                    hi = (idx <= 3u) ? hi : 0u;
                }
                fw[pr] = lo | (hi << 16);
            }
        }
        return __builtin_bit_cast(bf16x8, fw);
    };

    // stage one (db,c) unit (10 KB) into buf pb: 5 x 1KB chunks per wave
    auto stage = [&](int pb, int db, int c) {
        const char* src = wpb + (size_t)(db * 9 + c) * UNITB + (size_t)l * 16;
        char* dst = &ldsB[pb][0];
        #pragma unroll
        for (int ch = 0; ch < 5; ++ch)
            gload_lds16(src + (size_t)(wid + 2 * ch) * 1024, dst + (wid + 2 * ch) * 1024);
    };

    // prologue: x for db0, stage unit 0 into buf 0
    xload(db0);
    stage(0, db0, 0);

    int p = 0;
    #pragma unroll 1
    for (int u = 0; u < NU; ++u) {
        const int db = db0 + u / 9;
        const int c  = u - 9 * (u / 9);
        const bool hasNext = (u + 1 < NU);
        if (hasNext)
            stage(p ^ 1, db0 + (u + 1) / 9, (u + 1) % 9);   // 5 loads, stays in flight
        const bool xl = (c == 4) && (db + 1 < db1);
        if (xl) xload(db + 1);                              // 4 loads (counted below)
        if (c == 0) {
            evalkh(0);
            evalkh(1);                        // db==24: stale xq[1], unused below
        }
        // counted wait: retire stage(u) (issued last iter); keep stage(u+1) in flight
        if (!hasNext)   { asm volatile("s_waitcnt vmcnt(0)" ::: "memory"); }
        else if (xl)    { asm volatile("s_waitcnt vmcnt(9)" ::: "memory"); }
        else            { asm volatile("s_waitcnt vmcnt(5)" ::: "memory"); }
        __builtin_amdgcn_s_barrier();            // A: partner's stage(u) also retired
        __builtin_amdgcn_sched_barrier(0);       // rule 18: no hoist above the wait
        #pragma unroll
        for (int kh = 0; kh < 2; ++kh) {
            if (kh == 0 || db < 24) {
                const bf16x8 a = buildA(kh, c);
                const char* bp = &ldsB[p][kh * 5120] + l * 16;
                #pragma unroll
                for (int nt = 0; nt < 5; ++nt) {
                    const bf16x8 b = *(const bf16x8*)(bp + nt * 1024);
                    acc[nt] = __builtin_amdgcn_mfma_f32_32x32x16_bf16(a, b, acc[nt], 0, 0, 0);
                }
            }
        }
        __builtin_amdgcn_sched_barrier(0);       // no sink of reads below barrier B
        __builtin_amdgcn_s_barrier();            // B: reads done before next stage overwrite
        p ^= 1;
    }

    // ---- store: C/D 32x32: col = nt*32 + la, row = (r&3) + 8*(r>>2) + 4*lb --
    float* pp = part + (size_t)y * BATCH * NOUTC;
    const int rowb = blockIdx.x * 64 + wid * 32;
    #pragma unroll
    for (int nt = 0; nt < 5; ++nt) {
        #pragma unroll
        for (int r = 0; r < 16; ++r) {
            const int rl = (r & 3) + 8 * (r >> 2) + 4 * lb;
            pp[(size_t)(rowb + rl) * NOUTC + nt * 32 + la] = acc[nt][r];
        }
    }
}

// ---------------- epilogue MLP: sum partials, tanh -> 16x8 -> tanh -> 8x1 ----
__global__ void k_epi(const float* __restrict__ part, const float* __restrict__ w1,
                      const float* __restrict__ b1, const float* __restrict__ w2,
                      const float* __restrict__ b2, float* __restrict__ out) {
    int t = blockIdx.x * blockDim.x + threadIdx.x;
    if (t >= BATCH * HEADS) return;
    int b = t / HEADS;
    int h = t - b * HEADS;
    const f32x4* P = (const f32x4*)part;
    const int vbase = b * (NOUTC / 4) + h * 4;
    float y[16];
    #pragma unroll
    for (int c4 = 0; c4 < 4; ++c4) {
        f32x4 v = P[vbase + c4];
        #pragma unroll
        for (int s = 1; s < KSPLIT; ++s) {
            f32x4 v2 = P[(size_t)s * BATCH * (NOUTC / 4) + vbase + c4];
            v.x += v2.x; v.y += v2.y; v.z += v2.z; v.w += v2.w;
        }
        y[c4 * 4 + 0] = tanhf(v.x); y[c4 * 4 + 1] = tanhf(v.y);
        y[c4 * 4 + 2] = tanhf(v.z); y[c4 * 4 + 3] = tanhf(v.w);
    }
    float oacc = b2[h];
    #pragma unroll
    for (int p = 0; p < 8; ++p) {
        float a = b1[h * 8 + p];
        const float* wr = w1 + ((size_t)h * 8 + p) * 16;
        #pragma unroll
        for (int o = 0; o < 16; ++o) a = fmaf(y[o], wr[o], a);
        oacc = fmaf(tanhf(a), w2[h * 8 + p], oacc);
    }
    out[t] = oacc;
}

extern "C" void kernel_launch(void* const* d_in, const int* in_sizes, int n_in,
                              void* d_out, int out_size, void* d_ws, size_t ws_size,
                              hipStream_t stream) {
    const float* x          = (const float*)d_in[0];
    const float* gridp      = (const float*)d_in[1];
    const float* coef       = (const float*)d_in[2];
    const float* scale_base = (const float*)d_in[3];
    const float* scale_sp   = (const float*)d_in[4];
    const float* mask       = (const float*)d_in[5];
    const float* w1         = (const float*)d_in[6];
    const float* b1         = (const float*)d_in[7];
    const float* w2         = (const float*)d_in[8];
    const float* b2         = (const float*)d_in[9];
    float* out = (float*)d_out;

    char* ws = (char*)d_ws;
    float* part        = (float*)ws;                          // 5*16384*160*4 = 52,428,800 B
    unsigned short* Wp = (unsigned short*)(ws + 52428800);    // 225*32*160*2  =  2,304,000 B

    k_wprep<<<dim3((NUNITS * 32 * NOUTC + 255) / 256), dim3(256), 0, stream>>>(coef, scale_base, scale_sp, mask, Wp);
    k_fused<<<dim3(BATCH / 64, KSPLIT), dim3(128), 0, stream>>>(x, gridp, Wp, part);
    k_epi  <<<dim3((BATCH * HEADS + 255) / 256), dim3(256), 0, stream>>>(part, w1, b1, w2, b2, out);
}

// Round 12
// 127.100 us; speedup vs baseline: 2.1531x; 1.0715x over previous
//
#include <hip/hip_runtime.h>

#define IN_DIM 784
#define NDB 25                 // dim-blocks of 32 (784 = 24*32 + 16 exactly)
#define NUNITS (NDB*9)         // 225 (db,c) units of 32 k
#define BATCH 16384
#define NOUTC 160              // HEADS*OUT_DIM
#define HEADS 10
#define KSPLIT 5
#define DBPY 5                 // db per y-slice (5*5 = 25)
#define NU (DBPY*9)            // 45 units per slice
#define UNITB 10240            // bytes of B per (db,c) unit: 32k x 160n x 2B

typedef __attribute__((ext_vector_type(8))) short bf16x8;
typedef __attribute__((ext_vector_type(4))) float f32x4;
typedef __attribute__((ext_vector_type(16))) float f32x16;
typedef __attribute__((ext_vector_type(4))) unsigned int u32x4;

__device__ __forceinline__ unsigned short f2bf(float f) {
    unsigned u = __builtin_bit_cast(unsigned, f);
    unsigned r = 0x7FFFu + ((u >> 16) & 1u);
    return (unsigned short)((u + r) >> 16);
}

// ---------------- weight packing: W -> 32x32x16 MFMA B-fragment layout -------
// unit kc = db*9 + c; fragment f = (kc*2 + kh)*5 + nt.
// B-frag: lane l elem j: d = db*32 + kh*16 + (l>>5)*8 + j ; n = nt*32 + (l&31)
// 1/6 spline constant folded here. [layout verified r5/r9/r10/r11 pass]
__global__ void k_wprep(const float* __restrict__ coef, const float* __restrict__ scale_base,
                        const float* __restrict__ scale_sp, const float* __restrict__ mask,
                        unsigned short* __restrict__ Wp) {
    int tid = blockIdx.x * blockDim.x + threadIdx.x;
    if (tid >= NUNITS * 32 * NOUTC) return;     // 1,152,000
    int frag = tid >> 9;
    int rem  = tid & 511;
    int l = rem >> 3, j = rem & 7;
    int nt = frag % 5;
    int t2 = frag / 5;
    int kh = t2 & 1;
    int kc = t2 >> 1;
    int db = kc / 9, c = kc - db * 9;
    int d = db * 32 + kh * 16 + ((l >> 5) << 3) + j;
    int n = nt * 32 + (l & 31);
    float v = 0.f;
    if (d < IN_DIM) {
        int h = n >> 4, o = n & 15;
        size_t base = ((size_t)h * IN_DIM + d) * 16 + o;
        float m = mask[base];
        v = (c == 0) ? scale_base[base] * m
                     : coef[base * 8 + (c - 1)] * scale_sp[base] * m * 0.16666667f;
    }
    Wp[tid] = f2bf(v);
}

// ---------------- fused: A-frags AND B-frags in registers, no LDS, no barriers
// 64 thr = 1 wave per block; wave owns rows [bx*32, +32) x all 160 cols.
// B loaded global->VGPR double-buffered one unit ahead (Wp is L2-resident on
// every XCD: 2.3 MB < 4 MB). No __syncthreads anywhere -> no convoy; the
// compiler pipelines loads across the manually unrolled-by-2 unit loop.
__global__ void __launch_bounds__(64, 2) k_fused(const float* __restrict__ x,
                                                 const float* __restrict__ gridp,
                                                 const unsigned short* __restrict__ Wp,
                                                 float* __restrict__ part) {
    const int l = threadIdx.x & 63;
    const int la = l & 31, lb = l >> 5;
    const int row0 = blockIdx.x * 32 + la;     // this lane's row
    const int y = blockIdx.y;
    const int db0 = y * DBPY, db1 = db0 + DBPY;

    const float g0 = gridp[0];
    const float ih = 1.f / (gridp[1] - g0);
    const float nihg0 = -g0 * ih;

    f32x16 acc[5];
    #pragma unroll
    for (int nt = 0; nt < 5; ++nt)
        #pragma unroll
        for (int j = 0; j < 16; ++j) acc[nt][j] = 0.f;

    const float* xrow = x + (size_t)row0 * IN_DIM;
    const char* wpb = (const char*)Wp + (size_t)l * 16;

    // eval state per kh: 8 dims -> packed spline pair (w0,w1|w2,w3), packed m+8
    unsigned long long wp[2][8];
    unsigned mp[2][2];          // m+8 bytes, 4 per dword
    unsigned sf[2][4];          // packed silu (live only within c==0 phase)
    f32x4 xq[2][2];

    auto xload = [&](int db) {
        #pragma unroll
        for (int kh = 0; kh < 2; ++kh) {
            if (db * 32 + kh * 16 < IN_DIM) {
                const int d0 = db * 32 + kh * 16 + lb * 8;
                xq[kh][0] = *(const f32x4*)(xrow + d0);
                xq[kh][1] = *(const f32x4*)(xrow + d0 + 4);
            }
        }
    };

    auto evalkh = [&](int kh) {
        float sil8[8];
        unsigned m0 = 0u, m1 = 0u;
        #pragma unroll
        for (int jj = 0; jj < 8; ++jj) {
            const float xv = (jj < 4) ? xq[kh][0][jj] : xq[kh][1][jj - 4];
            const float u = fmaf(xv, ih, nihg0);
            const float fm = floorf(u);
            int m = (int)fm;
            m = m < -8 ? -8 : (m > 24 ? 24 : m);
            const float t = u - fm;
            const float w0 = t * t * t;
            const float w1 = fmaf(fmaf(fmaf(-3.f, t, 3.f), t, 3.f), t, 1.f);
            const float w2 = fmaf(fmaf(3.f, t, -6.f) * t, t, 4.f);
            const float omt = 1.f - t;
            const float w3 = omt * omt * omt;
            const float den = 1.f + __expf(-xv);
            float inv; asm("v_rcp_f32 %0, %1" : "=v"(inv) : "v"(den));
            sil8[jj] = xv * inv;
            unsigned p01, p23;
            asm("v_cvt_pk_bf16_f32 %0, %1, %2" : "=v"(p01) : "v"(w0), "v"(w1));
            asm("v_cvt_pk_bf16_f32 %0, %1, %2" : "=v"(p23) : "v"(w2), "v"(w3));
            wp[kh][jj] = (unsigned long long)p01 | ((unsigned long long)p23 << 32);
            const unsigned mb = (unsigned)(m + 8);
            if (jj < 4) m0 |= mb << (jj * 8); else m1 |= mb << ((jj - 4) * 8);
        }
        mp[kh][0] = m0; mp[kh][1] = m1;
        #pragma unroll
        for (int pr = 0; pr < 4; ++pr) {
            unsigned ps;
            asm("v_cvt_pk_bf16_f32 %0, %1, %2" : "=v"(ps) : "v"(sil8[2*pr]), "v"(sil8[2*pr+1]));
            sf[kh][pr] = ps;
        }
    };

    // A-frag build: elem j of plane c = wsel[m_j-(c-1)] (0 if out of [0,3])
    auto buildA = [&](int kh, int c) -> bf16x8 {
        u32x4 fw;
        if (c == 0) {
            fw = (u32x4){sf[kh][0], sf[kh][1], sf[kh][2], sf[kh][3]};
        } else {
            const unsigned sub = (unsigned)(7 + c);   // idx = (m+8) - (7+c)
            #pragma unroll
            for (int pr = 0; pr < 4; ++pr) {
                unsigned lo, hi;
                {
                    const int j = 2 * pr;
                    const unsigned stored = (mp[kh][j >> 2] >> ((j & 3) * 8)) & 0xFFu;
                    const unsigned idx = stored - sub;            // wraps if negative
                    const unsigned amt = (idx << 4) & 63u;
                    lo = (unsigned)(wp[kh][j] >> amt) & 0xFFFFu;
                    lo = (idx <= 3u) ? lo : 0u;
                }
                {
                    const int j = 2 * pr + 1;
                    const unsigned stored = (mp[kh][j >> 2] >> ((j & 3) * 8)) & 0xFFu;
                    const unsigned idx = stored - sub;
                    const unsigned amt = (idx << 4) & 63u;
                    hi = (unsigned)(wp[kh][j] >> amt) & 0xFFFFu;
                    hi = (idx <= 3u) ? hi : 0u;
                }
                fw[pr] = lo | (hi << 16);
            }
        }
        return __builtin_bit_cast(bf16x8, fw);
    };

    // load one unit's 10 B-fragments into a register buffer (global -> VGPR)
    auto loadB = [&](bf16x8 (&bf)[10], int u) {
        const char* src = wpb + (size_t)(db0 * 9 + u) * UNITB;
        #pragma unroll
        for (int i = 0; i < 10; ++i)
            bf[i] = *(const bf16x8*)(src + i * 1024);
    };

    auto compute = [&](int u, const bf16x8 (&bf)[10]) {
        const int db = db0 + u / 9;
        const int c  = u - 9 * (u / 9);
        if (c == 0) {
            evalkh(0);
            evalkh(1);                        // db==24: stale xq[1], unused below
        }
        if (c == 4 && db + 1 < db1) xload(db + 1);
        #pragma unroll
        for (int kh = 0; kh < 2; ++kh) {
            if (kh == 0 || db < 24) {
                const bf16x8 a = buildA(kh, c);
                #pragma unroll
                for (int nt = 0; nt < 5; ++nt)
                    acc[nt] = __builtin_amdgcn_mfma_f32_32x32x16_bf16(a, bf[kh * 5 + nt], acc[nt], 0, 0, 0);
            }
        }
    };

    // prologue + unroll-2 pipelined unit loop (NU = 45, odd)
    bf16x8 bA[10], bB[10];
    xload(db0);
    loadB(bA, 0);
    #pragma unroll 1
    for (int u = 0; u + 1 < NU; u += 2) {
        loadB(bB, u + 1);
        compute(u, bA);
        if (u + 2 < NU) loadB(bA, u + 2);
        compute(u + 1, bB);
    }
    compute(NU - 1, bA);

    // ---- store: C/D 32x32: col = nt*32 + la, row = (r&3) + 8*(r>>2) + 4*lb --
    float* pp = part + (size_t)y * BATCH * NOUTC;
    const int rowb = blockIdx.x * 32;
    #pragma unroll
    for (int nt = 0; nt < 5; ++nt) {
        #pragma unroll
        for (int r = 0; r < 16; ++r) {
            const int rl = (r & 3) + 8 * (r >> 2) + 4 * lb;
            pp[(size_t)(rowb + rl) * NOUTC + nt * 32 + la] = acc[nt][r];
        }
    }
}

// ---------------- epilogue MLP: sum partials, tanh -> 16x8 -> tanh -> 8x1 ----
__global__ void k_epi(const float* __restrict__ part, const float* __restrict__ w1,
                      const float* __restrict__ b1, const float* __restrict__ w2,
                      const float* __restrict__ b2, float* __restrict__ out) {
    int t = blockIdx.x * blockDim.x + threadIdx.x;
    if (t >= BATCH * HEADS) return;
    int b = t / HEADS;
    int h = t - b * HEADS;
    const f32x4* P = (const f32x4*)part;
    const int vbase = b * (NOUTC / 4) + h * 4;
    float y[16];
    #pragma unroll
    for (int c4 = 0; c4 < 4; ++c4) {
        f32x4 v = P[vbase + c4];
        #pragma unroll
        for (int s = 1; s < KSPLIT; ++s) {
            f32x4 v2 = P[(size_t)s * BATCH * (NOUTC / 4) + vbase + c4];
            v.x += v2.x; v.y += v2.y; v.z += v2.z; v.w += v2.w;
        }
        y[c4 * 4 + 0] = tanhf(v.x); y[c4 * 4 + 1] = tanhf(v.y);
        y[c4 * 4 + 2] = tanhf(v.z); y[c4 * 4 + 3] = tanhf(v.w);
    }
    float oacc = b2[h];
    #pragma unroll
    for (int p = 0; p < 8; ++p) {
        float a = b1[h * 8 + p];
        const float* wr = w1 + ((size_t)h * 8 + p) * 16;
        #pragma unroll
        for (int o = 0; o < 16; ++o) a = fmaf(y[o], wr[o], a);
        oacc = fmaf(tanhf(a), w2[h * 8 + p], oacc);
    }
    out[t] = oacc;
}

extern "C" void kernel_launch(void* const* d_in, const int* in_sizes, int n_in,
                              void* d_out, int out_size, void* d_ws, size_t ws_size,
                              hipStream_t stream) {
    const float* x          = (const float*)d_in[0];
    const float* gridp      = (const float*)d_in[1];
    const float* coef       = (const float*)d_in[2];
    const float* scale_base = (const float*)d_in[3];
    const float* scale_sp   = (const float*)d_in[4];
    const float* mask       = (const float*)d_in[5];
    const float* w1         = (const float*)d_in[6];
    const float* b1         = (const float*)d_in[7];
    const float* w2         = (const float*)d_in[8];
    const float* b2         = (const float*)d_in[9];
    float* out = (float*)d_out;

    char* ws = (char*)d_ws;
    float* part        = (float*)ws;                          // 5*16384*160*4 = 52,428,800 B
    unsigned short* Wp = (unsigned short*)(ws + 52428800);    // 225*32*160*2  =  2,304,000 B

    k_wprep<<<dim3((NUNITS * 32 * NOUTC + 255) / 256), dim3(256), 0, stream>>>(coef, scale_base, scale_sp, mask, Wp);
    k_fused<<<dim3(BATCH / 32, KSPLIT), dim3(64), 0, stream>>>(x, gridp, Wp, part);
    k_epi  <<<dim3((BATCH * HEADS + 255) / 256), dim3(256), 0, stream>>>(part, w1, b1, w2, b2, out);
}